// Round 2
// baseline (603.635 us; speedup 1.0000x reference)
//
#include <hip/hip_runtime.h>

#define NN 100000
#define NE 1600000

// ---------------- degree / normalization ----------------
__global__ __launch_bounds__(256) void k_init_deg(float* __restrict__ deg) {
    int i = blockIdx.x * 256 + threadIdx.x;
    if (i < NN) deg[i] = 1.0f;  // self-loop weight folded in
}

__global__ __launch_bounds__(256) void k_accum_deg(const int* __restrict__ dst,
                                                   const float* __restrict__ w,
                                                   float* __restrict__ deg) {
    int e = blockIdx.x * 256 + threadIdx.x;  // grid is exact (NE/256)
    atomicAdd(&deg[dst[e]], w[e]);
}

__global__ __launch_bounds__(256) void k_rsqrt(float* __restrict__ deg) {
    int i = blockIdx.x * 256 + threadIdx.x;
    if (i < NN) {
        float d = deg[i];
        deg[i] = d > 0.0f ? rsqrtf(d) : 0.0f;
    }
}

// ---------------- h1 = x @ W1   (x:[NN,128], W1:[128,64]) ----------------
__global__ __launch_bounds__(256) void k_gemm1(const float* __restrict__ x,
                                               const float* __restrict__ W,
                                               float* __restrict__ h) {
    __shared__ float Ws[128 * 64];   // 32 KB
    __shared__ float xs[16][128];    // 8 KB
    int tid  = threadIdx.x;
    int row0 = blockIdx.x * 16;      // NN % 16 == 0

    for (int i = tid; i < 128 * 64; i += 256) Ws[i] = W[i];
    for (int i = tid; i < 16 * 128; i += 256) xs[i >> 7][i & 127] = x[row0 * 128 + i];
    __syncthreads();

    int col = tid & 63;
    int rb  = (tid >> 6) << 2;  // 4 rows per thread
    float a0 = 0.f, a1 = 0.f, a2 = 0.f, a3 = 0.f;
    #pragma unroll
    for (int k = 0; k < 128; ++k) {
        float wv = Ws[k * 64 + col];   // 64 consecutive -> 2-way (free)
        a0 = fmaf(xs[rb + 0][k], wv, a0);  // broadcast
        a1 = fmaf(xs[rb + 1][k], wv, a1);
        a2 = fmaf(xs[rb + 2][k], wv, a2);
        a3 = fmaf(xs[rb + 3][k], wv, a3);
    }
    float* hp = h + (row0 + rb) * 64 + col;
    hp[0]   = a0;
    hp[64]  = a1;
    hp[128] = a2;
    hp[192] = a3;
}

// ---------------- x_emb init: bias + self-loop message ----------------
__global__ __launch_bounds__(256) void k_init1(const float* __restrict__ h1,
                                               const float* __restrict__ dis,
                                               const float* __restrict__ b1,
                                               float* __restrict__ xemb) {
    int idx = blockIdx.x * 256 + threadIdx.x;  // grid exact: NN*64/256
    int i = idx >> 6;
    float di = dis[i];
    xemb[idx] = fmaf(di * di, h1[idx], b1[idx & 63]);
}

// ---------------- layer-1 scatter: one wave per edge, lane = feature ----------------
__global__ __launch_bounds__(256) void k_scatter1(const int* __restrict__ src,
                                                  const int* __restrict__ dst,
                                                  const float* __restrict__ w,
                                                  const float* __restrict__ dis,
                                                  const float* __restrict__ h1,
                                                  float* __restrict__ xemb) {
    int t = blockIdx.x * 256 + threadIdx.x;  // grid exact: NE*64/256
    int e = t >> 6;
    int f = t & 63;
    int s = src[e], d = dst[e];
    float norm = dis[s] * w[e] * dis[d];
    atomicAdd(&xemb[d * 64 + f], norm * h1[s * 64 + f]);
}

// ---------------- h3 = relu(x_emb) @ W2   (W2:[64,16]) ----------------
__global__ __launch_bounds__(256) void k_gemm2(const float* __restrict__ xemb,
                                               const float* __restrict__ W,
                                               float* __restrict__ h3) {
    __shared__ float Ws[64 * 16];   // 4 KB
    __shared__ float xs[16][65];    // padded vs 4-way conflict
    int tid  = threadIdx.x;
    int row0 = blockIdx.x * 16;

    for (int i = tid; i < 64 * 16; i += 256) Ws[i] = W[i];
    for (int i = tid; i < 16 * 64; i += 256) {
        float v = xemb[row0 * 64 + i];
        xs[i >> 6][i & 63] = v > 0.0f ? v : 0.0f;  // fused ReLU
    }
    __syncthreads();

    int col = tid & 15;
    int r   = tid >> 4;
    float a = 0.f;
    #pragma unroll
    for (int k = 0; k < 64; ++k) a = fmaf(xs[r][k], Ws[k * 16 + col], a);
    h3[(row0 + r) * 16 + col] = a;
}

// ---------------- out init: bias + self-loop message ----------------
__global__ __launch_bounds__(256) void k_init2(const float* __restrict__ h3,
                                               const float* __restrict__ dis,
                                               const float* __restrict__ b2,
                                               float* __restrict__ out) {
    int idx = blockIdx.x * 256 + threadIdx.x;  // grid exact: NN*16/256
    int i = idx >> 4;
    float di = dis[i];
    out[idx] = fmaf(di * di, h3[idx], b2[idx & 15]);
}

// ---------------- layer-2 scatter: 16 lanes per edge ----------------
__global__ __launch_bounds__(256) void k_scatter2(const int* __restrict__ src,
                                                  const int* __restrict__ dst,
                                                  const float* __restrict__ w,
                                                  const float* __restrict__ dis,
                                                  const float* __restrict__ h3,
                                                  float* __restrict__ out) {
    int t = blockIdx.x * 256 + threadIdx.x;  // grid exact: NE*16/256
    int e = t >> 4;
    int f = t & 15;
    int s = src[e], d = dst[e];
    float norm = dis[s] * w[e] * dis[d];
    atomicAdd(&out[d * 16 + f], norm * h3[s * 16 + f]);
}

extern "C" void kernel_launch(void* const* d_in, const int* in_sizes, int n_in,
                              void* d_out, int out_size, void* d_ws, size_t ws_size,
                              hipStream_t stream) {
    const float* x  = (const float*)d_in[0];
    const int*   ei = (const int*)d_in[1];
    const float* w  = (const float*)d_in[2];
    const float* W1 = (const float*)d_in[3];
    const float* b1 = (const float*)d_in[4];
    const float* W2 = (const float*)d_in[5];
    const float* b2 = (const float*)d_in[6];
    const int* src = ei;
    const int* dst = ei + NE;

    float* out2 = (float*)d_out;               // [NN,16]  (output 0)
    float* xemb = (float*)d_out + NN * 16;     // [NN,64]  (output 1, also layer-1 accumulator)

    float* dis = (float*)d_ws;                 // NN floats (deg -> rsqrt in place)
    float* h1  = dis + NN;                     // NN*64
    float* h3  = h1 + (size_t)NN * 64;         // NN*16   (total ws use: 32.4 MB)

    k_init_deg <<<(NN + 255) / 256, 256, 0, stream>>>(dis);
    k_accum_deg<<<NE / 256,        256, 0, stream>>>(dst, w, dis);
    k_rsqrt    <<<(NN + 255) / 256, 256, 0, stream>>>(dis);

    k_gemm1    <<<NN / 16,          256, 0, stream>>>(x, W1, h1);
    k_init1    <<<NN * 64 / 256,    256, 0, stream>>>(h1, dis, b1, xemb);
    k_scatter1 <<<NE * 64 / 256,    256, 0, stream>>>(src, dst, w, dis, h1, xemb);

    k_gemm2    <<<NN / 16,          256, 0, stream>>>(xemb, W2, h3);
    k_init2    <<<NN * 16 / 256,    256, 0, stream>>>(h3, dis, b2, out2);
    k_scatter2 <<<NE * 16 / 256,    256, 0, stream>>>(src, dst, w, dis, h3, out2);
}

// Round 3
// 436.626 us; speedup vs baseline: 1.3825x; 1.3825x over previous
//
#include <hip/hip_runtime.h>

#define NN 100000
#define NE 1600000
#define NB_SCAN 391   // ceil(NN/256)

// ---------------- init: deg=1 (self-loop), hist=0 ----------------
__global__ __launch_bounds__(256) void k_init(float* __restrict__ deg, int* __restrict__ cursor) {
    int i = blockIdx.x * 256 + threadIdx.x;
    if (i < NN) { deg[i] = 1.0f; cursor[i] = 0; }
}

// ---------------- weighted degree + integer in-degree histogram ----------------
__global__ __launch_bounds__(256) void k_accum(const int* __restrict__ dst,
                                               const float* __restrict__ w,
                                               float* __restrict__ deg,
                                               int* __restrict__ cursor) {
    int e = blockIdx.x * 256 + threadIdx.x;  // grid exact NE/256
    int d = dst[e];
    atomicAdd(&deg[d], w[e]);
    atomicAdd(&cursor[d], 1);
}

__global__ __launch_bounds__(256) void k_rsqrt(float* __restrict__ deg) {
    int i = blockIdx.x * 256 + threadIdx.x;
    if (i < NN) {
        float d = deg[i];
        deg[i] = d > 0.0f ? rsqrtf(d) : 0.0f;
    }
}

// ---------------- scan step 1: per-block exclusive scan of counts ----------------
__global__ __launch_bounds__(256) void k_scan_block(const int* __restrict__ cnt,
                                                    int* __restrict__ row_ptr,
                                                    int* __restrict__ bsum) {
    __shared__ int s[256];
    int t = threadIdx.x;
    int gid = blockIdx.x * 256 + t;
    s[t] = (gid < NN) ? cnt[gid] : 0;
    __syncthreads();
    #pragma unroll
    for (int off = 1; off < 256; off <<= 1) {
        int add = (t >= off) ? s[t - off] : 0;
        __syncthreads();
        s[t] += add;
        __syncthreads();
    }
    if (gid < NN) row_ptr[gid] = (t == 0) ? 0 : s[t - 1];
    if (t == 255) bsum[blockIdx.x] = s[255];
}

// ---------------- scan step 2: exclusive scan of 391 block sums ----------------
__global__ __launch_bounds__(512) void k_scan_bsum(int* __restrict__ bsum) {
    __shared__ int s[512];
    int t = threadIdx.x;
    s[t] = (t < NB_SCAN) ? bsum[t] : 0;
    __syncthreads();
    #pragma unroll
    for (int off = 1; off < 512; off <<= 1) {
        int add = (t >= off) ? s[t - off] : 0;
        __syncthreads();
        s[t] += add;
        __syncthreads();
    }
    if (t < NB_SCAN) bsum[t] = (t == 0) ? 0 : s[t - 1];
}

// ---------------- scan step 3: add block offsets; cursor = row start ----------------
__global__ __launch_bounds__(256) void k_scan_add(int* __restrict__ row_ptr,
                                                  const int* __restrict__ bsum,
                                                  int* __restrict__ cursor) {
    int gid = blockIdx.x * 256 + threadIdx.x;
    if (gid < NN) {
        int v = row_ptr[gid] + bsum[blockIdx.x];
        row_ptr[gid] = v;
        cursor[gid] = v;
    }
    if (gid == 0) row_ptr[NN] = NE;
}

// ---------------- CSR fill: (src, norm) packed per slot ----------------
__global__ __launch_bounds__(256) void k_fill(const int* __restrict__ src,
                                              const int* __restrict__ dst,
                                              const float* __restrict__ w,
                                              const float* __restrict__ dis,
                                              int* __restrict__ cursor,
                                              float2* __restrict__ epack) {
    int e = blockIdx.x * 256 + threadIdx.x;  // grid exact NE/256
    int s = src[e], d = dst[e];
    int pos = atomicAdd(&cursor[d], 1);
    float norm = dis[s] * w[e] * dis[d];
    epack[pos] = make_float2(__int_as_float(s), norm);
}

// ---------------- h1 = x @ W1  (x:[NN,128], W1:[128,64]), 80-row tiles ----------------
#define XPAD 136  // 128 + 8 pad: rg banks 0/8/16/24, conflict-free; keeps 16B align
#define FMA4(a, s, b) { a.x = fmaf(s, b.x, a.x); a.y = fmaf(s, b.y, a.y); \
                        a.z = fmaf(s, b.z, a.z); a.w = fmaf(s, b.w, a.w); }

__global__ __launch_bounds__(320) void k_gemm1(const float* __restrict__ x,
                                               const float* __restrict__ W,
                                               float* __restrict__ h) {
    __shared__ float xs[80 * XPAD];   // 43.5 KB
    __shared__ float Ws[128 * 64];    // 32 KB
    int tid  = threadIdx.x;
    int row0 = blockIdx.x * 80;       // NN = 80 * 1250 exact

    for (int j = tid; j < 2048; j += 320)            // W1: 8192 floats as float4
        ((float4*)Ws)[j] = ((const float4*)W)[j];
    for (int j = tid; j < 2560; j += 320) {          // x tile: 80 rows x 32 float4
        int r = j >> 5, kq = j & 31;
        *(float4*)&xs[r * XPAD + kq * 4] =
            *(const float4*)&x[(row0 + r) * 128 + kq * 4];
    }
    __syncthreads();

    int cg = tid & 15;        // col group: c0..c0+3
    int rg = tid >> 4;        // row group 0..19: r0..r0+3
    int c0 = cg * 4, r0 = rg * 4;

    float4 acc0 = {0,0,0,0}, acc1 = {0,0,0,0}, acc2 = {0,0,0,0}, acc3 = {0,0,0,0};
    #pragma unroll
    for (int kq = 0; kq < 32; ++kq) {
        float4 xv0 = *(const float4*)&xs[(r0 + 0) * XPAD + kq * 4];
        float4 xv1 = *(const float4*)&xs[(r0 + 1) * XPAD + kq * 4];
        float4 xv2 = *(const float4*)&xs[(r0 + 2) * XPAD + kq * 4];
        float4 xv3 = *(const float4*)&xs[(r0 + 3) * XPAD + kq * 4];
        float4 wv0 = *(const float4*)&Ws[(kq * 4 + 0) * 64 + c0];
        float4 wv1 = *(const float4*)&Ws[(kq * 4 + 1) * 64 + c0];
        float4 wv2 = *(const float4*)&Ws[(kq * 4 + 2) * 64 + c0];
        float4 wv3 = *(const float4*)&Ws[(kq * 4 + 3) * 64 + c0];
        FMA4(acc0, xv0.x, wv0); FMA4(acc0, xv0.y, wv1); FMA4(acc0, xv0.z, wv2); FMA4(acc0, xv0.w, wv3);
        FMA4(acc1, xv1.x, wv0); FMA4(acc1, xv1.y, wv1); FMA4(acc1, xv1.z, wv2); FMA4(acc1, xv1.w, wv3);
        FMA4(acc2, xv2.x, wv0); FMA4(acc2, xv2.y, wv1); FMA4(acc2, xv2.z, wv2); FMA4(acc2, xv2.w, wv3);
        FMA4(acc3, xv3.x, wv0); FMA4(acc3, xv3.y, wv1); FMA4(acc3, xv3.z, wv2); FMA4(acc3, xv3.w, wv3);
    }

    float* hp = h + (row0 + r0) * 64 + c0;
    *(float4*)(hp)        = acc0;
    *(float4*)(hp + 64)   = acc1;
    *(float4*)(hp + 128)  = acc2;
    *(float4*)(hp + 192)  = acc3;
}

// ---------------- layer-1 aggregation: one wave per node, lane = feature ----------------
__global__ __launch_bounds__(256) void k_agg1(const int* __restrict__ row_ptr,
                                              const float2* __restrict__ epack,
                                              const float* __restrict__ h1,
                                              const float* __restrict__ dis,
                                              const float* __restrict__ b1,
                                              float* __restrict__ xemb) {
    int n = (blockIdx.x * 256 + threadIdx.x) >> 6;  // grid exact: 25000*4 waves
    int f = threadIdx.x & 63;
    float di = dis[n];
    float acc = fmaf(di * di, h1[n * 64 + f], b1[f]);
    int j = row_ptr[n], end = row_ptr[n + 1];
    for (; j + 1 < end; j += 2) {   // 2-deep: two gathers in flight
        float2 p0 = epack[j], p1 = epack[j + 1];
        float v0 = h1[__float_as_int(p0.x) * 64 + f];
        float v1 = h1[__float_as_int(p1.x) * 64 + f];
        acc = fmaf(p0.y, v0, acc);
        acc = fmaf(p1.y, v1, acc);
    }
    if (j < end) {
        float2 p = epack[j];
        acc = fmaf(p.y, h1[__float_as_int(p.x) * 64 + f], acc);
    }
    xemb[n * 64 + f] = acc;
}

// ---------------- h3 = relu(x_emb) @ W2   (W2:[64,16]) ----------------
__global__ __launch_bounds__(256) void k_gemm2(const float* __restrict__ xemb,
                                               const float* __restrict__ W,
                                               float* __restrict__ h3) {
    __shared__ float Ws[64 * 16];
    __shared__ float xs[16][65];
    int tid  = threadIdx.x;
    int row0 = blockIdx.x * 16;

    for (int i = tid; i < 64 * 16; i += 256) Ws[i] = W[i];
    for (int i = tid; i < 16 * 64; i += 256) {
        float v = xemb[row0 * 64 + i];
        xs[i >> 6][i & 63] = v > 0.0f ? v : 0.0f;  // fused ReLU
    }
    __syncthreads();

    int col = tid & 15;
    int r   = tid >> 4;
    float a = 0.f;
    #pragma unroll
    for (int k = 0; k < 64; ++k) a = fmaf(xs[r][k], Ws[k * 16 + col], a);
    h3[(row0 + r) * 16 + col] = a;
}

// ---------------- layer-2 aggregation: wave = node, 16 feats x 4 edge groups ----------------
__global__ __launch_bounds__(256) void k_agg2(const int* __restrict__ row_ptr,
                                              const float2* __restrict__ epack,
                                              const float* __restrict__ h3,
                                              const float* __restrict__ dis,
                                              const float* __restrict__ b2,
                                              float* __restrict__ out) {
    int n    = (blockIdx.x * 256 + threadIdx.x) >> 6;
    int lane = threadIdx.x & 63;
    int f = lane & 15, g = lane >> 4;
    int start = row_ptr[n], end = row_ptr[n + 1];
    float acc = 0.f;
    for (int j = start + g; j < end; j += 4) {
        float2 p = epack[j];
        acc = fmaf(p.y, h3[__float_as_int(p.x) * 16 + f], acc);
    }
    acc += __shfl_xor(acc, 16, 64);   // reduce the 4 edge groups
    acc += __shfl_xor(acc, 32, 64);
    if (g == 0) {
        float di = dis[n];
        out[n * 16 + f] = fmaf(di * di, h3[n * 16 + f], b2[f]) + acc;
    }
}

extern "C" void kernel_launch(void* const* d_in, const int* in_sizes, int n_in,
                              void* d_out, int out_size, void* d_ws, size_t ws_size,
                              hipStream_t stream) {
    const float* x  = (const float*)d_in[0];
    const int*   ei = (const int*)d_in[1];
    const float* w  = (const float*)d_in[2];
    const float* W1 = (const float*)d_in[3];
    const float* b1 = (const float*)d_in[4];
    const float* W2 = (const float*)d_in[5];
    const float* b2 = (const float*)d_in[6];
    const int* src = ei;
    const int* dst = ei + NE;

    float* out2 = (float*)d_out;               // [NN,16]  output 0
    float* xemb = (float*)d_out + NN * 16;     // [NN,64]  output 1

    // workspace layout (~46.0 MB total), 16B-aligned partitions
    float*  dis     = (float*)d_ws;                    // NN
    float*  h1      = dis + NN;                        // NN*64
    float*  h3      = h1 + (size_t)NN * 64;            // NN*16
    float2* epack   = (float2*)(h3 + (size_t)NN * 16); // NE float2 (src, norm)
    int*    row_ptr = (int*)(epack + NE);              // NN+1
    int*    cursor  = row_ptr + NN + 1;                // NN
    int*    bsum    = cursor + NN;                     // 512

    // --- normalization + CSR build (shared by both layers) ---
    k_init      <<<(NN + 255) / 256, 256, 0, stream>>>(dis, cursor);
    k_accum     <<<NE / 256,         256, 0, stream>>>(dst, w, dis, cursor);
    k_rsqrt     <<<(NN + 255) / 256, 256, 0, stream>>>(dis);
    k_scan_block<<<NB_SCAN,          256, 0, stream>>>(cursor, row_ptr, bsum);
    k_scan_bsum <<<1,                512, 0, stream>>>(bsum);
    k_scan_add  <<<NB_SCAN,          256, 0, stream>>>(row_ptr, bsum, cursor);
    k_fill      <<<NE / 256,         256, 0, stream>>>(src, dst, w, dis, cursor, epack);

    // --- layer 1 ---
    k_gemm1     <<<NN / 80,          320, 0, stream>>>(x, W1, h1);
    k_agg1      <<<NN / 4,           256, 0, stream>>>(row_ptr, epack, h1, dis, b1, xemb);

    // --- layer 2 ---
    k_gemm2     <<<NN / 16,          256, 0, stream>>>(xemb, W2, h3);
    k_agg2      <<<NN / 4,           256, 0, stream>>>(row_ptr, epack, h3, dis, b2, out2);
}